// Round 7
// baseline (226.670 us; speedup 1.0000x reference)
//
#include <hip/hip_runtime.h>

namespace {

constexpr int HH  = 48;
constexpr int DIM = 384;
constexpr int NH  = 6;
constexpr int K3  = 27;
constexpr float L2E    = 1.44269504088896f;
constexpr float SCALE2 = 0.125f * L2E;          // 64^-0.5 * log2(e)

constexpr int TT     = 4;
constexpr int NPAD   = 224;                     // staged cols (216 + 8 pad)
constexpr int NT     = 7;                       // per-wave 16-col slabs (112 cols @ w*36)
constexpr int TILES1 = HH / TT;                 // 12
constexpr int TILES  = TILES1 * TILES1 * TILES1;// 1728
constexpr int NBLK   = 2 * NH * TILES;          // 20736 (div by 8)

typedef _Float16 half8  __attribute__((ext_vector_type(8)));
typedef _Float16 half2v __attribute__((ext_vector_type(2)));
typedef __fp16   fp16x2 __attribute__((ext_vector_type(2)));
typedef float    floatx4 __attribute__((ext_vector_type(4)));

__device__ __forceinline__ half2v pk(float a, float b) {
    fp16x2 t = __builtin_amdgcn_cvt_pkrtz(a, b);
    return __builtin_bit_cast(half2v, t);
}

// async global->LDS DMA, 16 B per lane; LDS dest = wave-uniform base + lane*16
__device__ __forceinline__ void gl_lds16(const float* g, void* l) {
    __builtin_amdgcn_global_load_lds(
        (const __attribute__((address_space(1))) unsigned int*)g,
        (__attribute__((address_space(3))) unsigned int*)l, 16, 0, 0);
}

__global__ __launch_bounds__(256, 2)
void natten_mfma5(const float* __restrict__ q, const float* __restrict__ k,
                  const float* __restrict__ rpb, const float* __restrict__ vv,
                  float* __restrict__ out)
{
    __shared__ float  k_lds[NPAD * 64];     // 57344 B f32, 16B-slot swizzled
    __shared__ float  logit_lds[64 * 28];   //  7168 B
    __shared__ float4 rv_lds[K3];           //   432 B   => 64944 B, 2 blocks/CU

    const int bid0 = blockIdx.x;
    const int bid  = (bid0 & 7) * (NBLK / 8) + (bid0 >> 3);   // bijective XCD swizzle

    const int n    = bid % NH;                 // head-fastest for L2 sharing
    const int tile = (bid / NH) % TILES;
    const int b    = bid / (NH * TILES);
    const int tz = (tile % TILES1) * TT;
    const int ty = ((tile / TILES1) % TILES1) * TT;
    const int tx = (tile / (TILES1 * TILES1)) * TT;

    const int tid = threadIdx.x;
    if (tid < K3) {
        rv_lds[tid] = make_float4(vv[tid * 3], vv[tid * 3 + 1], vv[tid * 3 + 2],
                                  rpb[n * K3 + tid] * L2E);
    }

    const int w = tid >> 6, lane = tid & 63;
    const int lrow = lane & 15, lgrp = lane >> 4;

    // ---- q loads first (plain vector loads to regs) ----
    const float* qp = q + (size_t)b * (HH * HH * HH) * DIM
        + (size_t)(((tx + w) * 48 + (ty + (lrow >> 2))) * 48 + (tz + (lrow & 3))) * DIM
        + n * 64 + lgrp * 8;
    const float4 qf0 = ((const float4*)qp)[0];
    const float4 qf1 = ((const float4*)qp)[1];
    const float4 qg0 = ((const float4*)(qp + 32))[0];
    const float4 qg1 = ((const float4*)(qp + 32))[1];

    // ---- k stage: 14 async DMA ops/wave, no VGPR payload ----
    // wave w stages cols [w*56, w*56+56); load i covers 4 cols (1 KiB).
    // lane: col = w*56 + i*4 + (lane>>4), slot sl = lane&15.
    // pre-swizzled source: fetch logical chunk t = sl ^ (col&7) so that the
    // LINEAR LDS write lands in the swizzled layout the GEMM reads.
    const float* kb = k + (size_t)b * (HH * HH * HH) * DIM + n * 64;
    {
        const int lo = lane >> 4, sl = lane & 15;
        int col = w * 56 + lo;
        int cx = col / 36, r36 = col - cx * 36;
        int cy = r36 / 6,  cz = r36 - cy * 6;
        char* dstbase = (char*)k_lds + w * 14336;
        #pragma unroll
        for (int i = 0; i < 14; ++i) {
            const int t  = sl ^ ((i * 4 + lo) & 7);    // (col&7) == (i*4+lo)&7, 56%8==0
            const int gx = tx + cx - 1, gy = ty + cy - 1, gz = tz + cz - 1;
            const int cgx = min(max(gx, 0), 47);
            const int cgy = min(max(gy, 0), 47);
            const int cgz = min(max(gz, 0), 47);
            gl_lds16(kb + (size_t)((cgx * 48 + cgy) * 48 + cgz) * DIM + t * 4,
                     dstbase + i * 1024);
            cz += 4;                                    // col += 4 (base-6 carries)
            if (cz >= 6) { cz -= 6; ++cy; if (cy >= 6) { cy -= 6; ++cx; } }
        }
    }

    // q convert while the 14 DMAs are still in flight (needs vmcnt(14) only)
    half8 a0, a1;
    ((half2v*)&a0)[0] = pk(qf0.x, qf0.y);
    ((half2v*)&a0)[1] = pk(qf0.z, qf0.w);
    ((half2v*)&a0)[2] = pk(qf1.x, qf1.y);
    ((half2v*)&a0)[3] = pk(qf1.z, qf1.w);
    ((half2v*)&a1)[0] = pk(qg0.x, qg0.y);
    ((half2v*)&a1)[1] = pk(qg0.z, qg0.w);
    ((half2v*)&a1)[2] = pk(qg1.x, qg1.y);
    ((half2v*)&a1)[3] = pk(qg1.z, qg1.w);
    __syncthreads();    // drains vmcnt + barrier

    // ---- GEMM: wave w covers cols [w*36, w*36+112); f32->f16 cvt on read ----
    const int cbase = w * 36 + lrow;
    const int m2 = (cbase & 7) << 4;                    // invariant under +16
    const char* cp = (char*)k_lds + cbase * 256;
    const int o0 = (lgrp * 32)       ^ m2;
    const int o1 = (lgrp * 32 + 16)  ^ m2;
    const int o2 = (128 + lgrp * 32) ^ m2;
    const int o3 = (128 + lgrp * 32 + 16) ^ m2;
    floatx4 acc[NT];
    #pragma unroll
    for (int nt = 0; nt < NT; ++nt) {
        const float4 u0 = *(const float4*)(cp + nt * 4096 + o0);
        const float4 u1 = *(const float4*)(cp + nt * 4096 + o1);
        const float4 u2 = *(const float4*)(cp + nt * 4096 + o2);
        const float4 u3 = *(const float4*)(cp + nt * 4096 + o3);
        half8 b0, b1;
        ((half2v*)&b0)[0] = pk(u0.x, u0.y);
        ((half2v*)&b0)[1] = pk(u0.z, u0.w);
        ((half2v*)&b0)[2] = pk(u1.x, u1.y);
        ((half2v*)&b0)[3] = pk(u1.z, u1.w);
        ((half2v*)&b1)[0] = pk(u2.x, u2.y);
        ((half2v*)&b1)[1] = pk(u2.z, u2.w);
        ((half2v*)&b1)[2] = pk(u3.x, u3.y);
        ((half2v*)&b1)[3] = pk(u3.z, u3.w);
        floatx4 c = {0.f, 0.f, 0.f, 0.f};
        c = __builtin_amdgcn_mfma_f32_16x16x32_f16(a0, b0, c, 0, 0, 0);
        c = __builtin_amdgcn_mfma_f32_16x16x32_f16(a1, b1, c, 0, 0, 0);
        acc[nt] = c;
    }

    // ---- scatter banded entries -> [64][28], masking globally-OOB columns ----
    // rel = nt*16+lrow = rx*36+ry*6+rz; col's position: (tx+w+rx-1, ty+ry-1, tz+rz-1)
    {
        const int ly6 = lrow >= 12 ? 2 : (lrow >= 6 ? 1 : 0);
        const int lz6 = lrow - ly6 * 6;
        const int base0 = (w * 16 + lgrp * 4) * 112;    // byte offset of row m(r=0)
        constexpr int Nx[NT] = {0, 0, 0, 1, 1, 2, 2};
        constexpr int Ny[NT] = {0, 2, 5, 2, 4, 1, 4};
        constexpr int Nz[NT] = {0, 4, 2, 0, 4, 2, 0};
        #pragma unroll
        for (int nt = 0; nt < NT; ++nt) {
            int rz = lz6 + Nz[nt];
            int ry = ly6 + Ny[nt];
            if (rz >= 6) { rz -= 6; ry += 1; }
            int rx = Nx[nt];
            if (ry >= 6) { ry -= 6; rx += 1; }
            const int dj = ry - lgrp;
            if (rx <= 2 && (unsigned)dj <= 2u) {
                const bool vx = (unsigned)(tx + w + rx - 1) < 48u;
                const bool vy = (unsigned)(ty + ry - 1) < 48u;
                const bool vz = (unsigned)(tz + rz - 1) < 48u;
                const float fm = (vx && vy && vz) ? 1.f : 0.f;   // zero-pad semantics
                const int sl0 = (rx * 3 + dj) * 3 + rz;          // slot(r) = sl0 - r
                #pragma unroll
                for (int r = 0; r < 4; ++r) {
                    if ((unsigned)(rz - r) <= 2u) {
                        *(float*)((char*)logit_lds + base0 + r * 112 + (sl0 - r) * 4)
                            = acc[nt][r] * fm;
                    }
                }
            }
        }
    }
    // wave w wrote exactly logit rows [16w,16w+16); same wave reads them below.

    // ---- softmax (exp2 domain): 4 threads/query, o = p mod 4 ----
    {
        const int qi = tid >> 2, p = tid & 3;
        const float* lp = logit_lds + qi * 28;
        float t[7];
        float mx = -1e30f;
        #pragma unroll
        for (int j = 0; j < 7; ++j) {
            const int o = p + 4 * j;
            if (o < K3) {
                t[j] = fmaf(lp[o], SCALE2, rv_lds[o].w);
                mx = fmaxf(mx, t[j]);
            }
        }
        mx = fmaxf(mx, __shfl_xor(mx, 1));
        mx = fmaxf(mx, __shfl_xor(mx, 2));
        float den = 0.f, n0 = 0.f, n1 = 0.f, n2 = 0.f;
        #pragma unroll
        for (int j = 0; j < 7; ++j) {
            const int o = p + 4 * j;
            if (o < K3) {
                const float e = __builtin_amdgcn_exp2f(t[j] - mx);
                const float4 rv = rv_lds[o];
                den += e;
                n0 = fmaf(e, rv.x, n0);
                n1 = fmaf(e, rv.y, n1);
                n2 = fmaf(e, rv.z, n2);
            }
        }
        den += __shfl_xor(den, 1); den += __shfl_xor(den, 2);
        n0  += __shfl_xor(n0, 1);  n0  += __shfl_xor(n0, 2);
        n1  += __shfl_xor(n1, 1);  n1  += __shfl_xor(n1, 2);
        n2  += __shfl_xor(n2, 1);  n2  += __shfl_xor(n2, 2);
        if (p < 3) {
            const float res = (p == 0 ? n0 : (p == 1 ? n1 : n2)) / den;
            out[((size_t)(b * 18 + n * 3 + p) * HH + (tx + (qi >> 4))) * (size_t)(HH * HH)
                + (size_t)(ty + ((qi >> 2) & 3)) * HH + (tz + (qi & 3))] = res;
        }
    }
}

} // namespace

extern "C" void kernel_launch(void* const* d_in, const int* in_sizes, int n_in,
                              void* d_out, int out_size, void* d_ws, size_t ws_size,
                              hipStream_t stream)
{
    (void)in_sizes; (void)n_in; (void)d_ws; (void)ws_size; (void)out_size;
    const float* q   = (const float*)d_in[0];
    const float* k   = (const float*)d_in[1];
    const float* rpb = (const float*)d_in[2];
    const float* vv  = (const float*)d_in[3];
    float* out = (float*)d_out;

    natten_mfma5<<<dim3(NBLK), dim3(256), 0, stream>>>(q, k, rpb, vv, out);
}

// Round 8
// 193.056 us; speedup vs baseline: 1.1741x; 1.1741x over previous
//
#include <hip/hip_runtime.h>

namespace {

constexpr int HH  = 48;
constexpr int DIM = 384;
constexpr int NH  = 6;
constexpr int K3  = 27;
constexpr float L2E    = 1.44269504088896f;
constexpr float SCALE2 = 0.125f * L2E;          // 64^-0.5 * log2(e)

constexpr int TT     = 4;
constexpr int NPAD   = 224;
constexpr int NT     = 7;                       // per-wave 16-col slabs (112 cols @ w*36)
constexpr int TILES1 = HH / TT;                 // 12
constexpr int TILES  = TILES1 * TILES1 * TILES1;// 1728
constexpr int NBLK   = 2 * NH * TILES;          // 20736 (div by 8)

typedef _Float16 half8  __attribute__((ext_vector_type(8)));
typedef _Float16 half2v __attribute__((ext_vector_type(2)));
typedef __fp16   fp16x2 __attribute__((ext_vector_type(2)));
typedef float    floatx4 __attribute__((ext_vector_type(4)));

__device__ __forceinline__ half2v pk(float a, float b) {
    fp16x2 t = __builtin_amdgcn_cvt_pkrtz(a, b);
    return __builtin_bit_cast(half2v, t);
}

__global__ __launch_bounds__(256, 4)
void natten_mfma6(const float* __restrict__ q, const float* __restrict__ k,
                  const float* __restrict__ rpb, const float* __restrict__ vv,
                  float* __restrict__ out)
{
    __shared__ _Float16 k_lds[NPAD * 64];    // 28672 B, swizzled
    __shared__ float    logit_lds[64 * 28];  //  7168 B
    __shared__ float4   rv_lds[K3];          //   432 B   total 36272 B -> 4 blocks/CU

    const int bid0 = blockIdx.x;
    const int bid  = (bid0 & 7) * (NBLK / 8) + (bid0 >> 3);   // bijective XCD swizzle

    const int n    = bid % NH;                 // head-fastest for L2 sharing
    const int tile = (bid / NH) % TILES;
    const int b    = bid / (NH * TILES);
    const int tz = (tile % TILES1) * TT;
    const int ty = ((tile / TILES1) % TILES1) * TT;
    const int tx = (tile / (TILES1 * TILES1)) * TT;

    const int tid = threadIdx.x;
    char* kl = (char*)k_lds;

    // compiler-tracked loads finish (use+waitcnt) before the asm region below
    if (tid < K3) {
        rv_lds[tid] = make_float4(vv[tid * 3], vv[tid * 3 + 1], vv[tid * 3 + 2],
                                  rpb[n * K3 + tid] * L2E);
    }

    const int w = tid >> 6, lane = tid & 63;
    const int lrow = lane & 15, lgrp = lane >> 4;

    // ============ phase A: ISSUE all 18 VMEM loads via volatile asm ============
    // q: 4 x dwordx4 from one base
    const float* qp = q + (size_t)b * (HH * HH * HH) * DIM
        + (size_t)(((tx + w) * 48 + (ty + (lrow >> 2))) * 48 + (tz + (lrow & 3))) * DIM
        + n * 64 + lgrp * 8;
    floatx4 qf0, qf1, qg0, qg1;
    asm volatile(
        "global_load_dwordx4 %0, %4, off\n\t"
        "global_load_dwordx4 %1, %4, off offset:16\n\t"
        "global_load_dwordx4 %2, %4, off offset:128\n\t"
        "global_load_dwordx4 %3, %4, off offset:144"
        : "=&v"(qf0), "=&v"(qf1), "=&v"(qg0), "=&v"(qg1)
        : "v"(qp) : "memory");

    // k: 7 cols/thread (col = tid>>3 + 32*it), 32 B each = 2 x dwordx4
    const float* kb = k + (size_t)b * (HH * HH * HH) * DIM + n * 64;
    const int col0 = tid >> 3;
    const int ch   = tid & 7;
    char* dst = kl + col0 * 128 + ((ch * 16) ^ ((col0 & 7) << 4));

    floatx4 F0[7], F1[7];
    float   MS[7];
    {
        int cx = 0, cy = col0 / 6, cz = col0 - (col0 / 6) * 6;
        #pragma unroll
        for (int it = 0; it < 7; ++it) {
            const int gx = tx + cx - 1, gy = ty + cy - 1, gz = tz + cz - 1;
            const bool valid = ((unsigned)gx < 48u) && ((unsigned)gy < 48u) &&
                               ((unsigned)gz < 48u);
            const int cgx = min(max(gx, 0), 47);
            const int cgy = min(max(gy, 0), 47);
            const int cgz = min(max(gz, 0), 47);
            const float* s = kb + (size_t)((cgx * 48 + cgy) * 48 + cgz) * DIM + ch * 8;
            asm volatile(
                "global_load_dwordx4 %0, %2, off\n\t"
                "global_load_dwordx4 %1, %2, off offset:16"
                : "=&v"(F0[it]), "=&v"(F1[it])
                : "v"(s) : "memory");
            MS[it] = valid ? 1.f : 0.f;
            cz += 2; if (cz >= 6) { cz -= 6; cy += 1; }     // +32 = (0,5,2) base-6
            cy += 5; if (cy >= 6) { cy -= 6; cx += 1; }
        }
    }

    // single drain: every payload quad is tied -> converts are data-dependent
    asm volatile("s_waitcnt vmcnt(0)"
        : "+v"(qf0), "+v"(qf1), "+v"(qg0), "+v"(qg1),
          "+v"(F0[0]), "+v"(F0[1]), "+v"(F0[2]), "+v"(F0[3]),
          "+v"(F0[4]), "+v"(F0[5]), "+v"(F0[6]),
          "+v"(F1[0]), "+v"(F1[1]), "+v"(F1[2]), "+v"(F1[3]),
          "+v"(F1[4]), "+v"(F1[5]), "+v"(F1[6])
        ::);
    __builtin_amdgcn_sched_barrier(0);

    // ============ phase B: convert + LDS write ============
    #pragma unroll
    for (int it = 0; it < 7; ++it) {
        const float m = MS[it];
        half8 h;
        ((half2v*)&h)[0] = pk(F0[it][0] * m, F0[it][1] * m);
        ((half2v*)&h)[1] = pk(F0[it][2] * m, F0[it][3] * m);
        ((half2v*)&h)[2] = pk(F1[it][0] * m, F1[it][1] * m);
        ((half2v*)&h)[3] = pk(F1[it][2] * m, F1[it][3] * m);
        *(half8*)(dst + it * 4096) = h;
    }

    half8 a0, a1;
    ((half2v*)&a0)[0] = pk(qf0[0], qf0[1]);
    ((half2v*)&a0)[1] = pk(qf0[2], qf0[3]);
    ((half2v*)&a0)[2] = pk(qf1[0], qf1[1]);
    ((half2v*)&a0)[3] = pk(qf1[2], qf1[3]);
    ((half2v*)&a1)[0] = pk(qg0[0], qg0[1]);
    ((half2v*)&a1)[1] = pk(qg0[2], qg0[3]);
    ((half2v*)&a1)[2] = pk(qg1[0], qg1[1]);
    ((half2v*)&a1)[3] = pk(qg1[2], qg1[3]);
    __syncthreads();                     // the only block-wide barrier

    // ============ GEMM: wave w covers cols [w*36, w*36+112) ============
    const int cbase = w * 36 + lrow;
    const int xm2 = (cbase & 7) << 4;                     // invariant under +16
    const char* bpA = kl + cbase * 128 + ((lgrp * 16) ^ xm2);
    const char* bpB = kl + cbase * 128 + ((lgrp * 16 + 64) ^ xm2);
    floatx4 acc[NT];
    #pragma unroll
    for (int nt = 0; nt < NT; ++nt) {
        const half8 b0 = *(const half8*)(bpA + nt * 2048);
        const half8 b1 = *(const half8*)(bpB + nt * 2048);
        floatx4 c = {0.f, 0.f, 0.f, 0.f};
        c = __builtin_amdgcn_mfma_f32_16x16x32_f16(a0, b0, c, 0, 0, 0);
        c = __builtin_amdgcn_mfma_f32_16x16x32_f16(a1, b1, c, 0, 0, 0);
        acc[nt] = c;
    }

    // ===== scatter banded entries -> [64][28]; intra-wave consumer, no barrier ====
    {
        const int ly6 = lrow >= 12 ? 2 : (lrow >= 6 ? 1 : 0);
        const int lz6 = lrow - ly6 * 6;
        const int base0 = (w * 16 + lgrp * 4) * 112;      // byte offset of row m(r=0)
        constexpr int Nx[NT] = {0, 0, 0, 1, 1, 2, 2};
        constexpr int Ny[NT] = {0, 2, 5, 2, 4, 1, 4};
        constexpr int Nz[NT] = {0, 4, 2, 0, 4, 2, 0};
        #pragma unroll
        for (int nt = 0; nt < NT; ++nt) {
            int rz = lz6 + Nz[nt];
            int ry = ly6 + Ny[nt];
            if (rz >= 6) { rz -= 6; ry += 1; }
            int rx = Nx[nt];
            if (ry >= 6) { ry -= 6; rx += 1; }
            const int dj = ry - lgrp;
            if (rx <= 2 && (unsigned)dj <= 2u) {
                const int sl0 = (rx * 3 + dj) * 3 + rz;   // slot(r) = sl0 - r
                #pragma unroll
                for (int r = 0; r < 4; ++r) {
                    if ((unsigned)(rz - r) <= 2u) {
                        *(float*)((char*)logit_lds + base0 + r * 112 + (sl0 - r) * 4)
                            = acc[nt][r];
                    }
                }
            }
        }
    }
    // wave w wrote exactly logit rows [16w,16w+16); same wave reads them below.

    // ============ softmax (exp2 domain): 4 threads/query, o = p mod 4 ============
    {
        const int qi = tid >> 2, p = tid & 3;
        const float* lp = logit_lds + qi * 28;
        float t[7];
        float mx = -1e30f;
        #pragma unroll
        for (int j = 0; j < 7; ++j) {
            const int o = p + 4 * j;
            if (o < K3) {
                t[j] = fmaf(lp[o], SCALE2, rv_lds[o].w);
                mx = fmaxf(mx, t[j]);
            }
        }
        mx = fmaxf(mx, __shfl_xor(mx, 1));
        mx = fmaxf(mx, __shfl_xor(mx, 2));
        float den = 0.f, n0 = 0.f, n1 = 0.f, n2 = 0.f;
        #pragma unroll
        for (int j = 0; j < 7; ++j) {
            const int o = p + 4 * j;
            if (o < K3) {
                const float e = __builtin_amdgcn_exp2f(t[j] - mx);
                const float4 rv = rv_lds[o];
                den += e;
                n0 = fmaf(e, rv.x, n0);
                n1 = fmaf(e, rv.y, n1);
                n2 = fmaf(e, rv.z, n2);
            }
        }
        den += __shfl_xor(den, 1); den += __shfl_xor(den, 2);
        n0  += __shfl_xor(n0, 1);  n0  += __shfl_xor(n0, 2);
        n1  += __shfl_xor(n1, 1);  n1  += __shfl_xor(n1, 2);
        n2  += __shfl_xor(n2, 1);  n2  += __shfl_xor(n2, 2);
        if (p < 3) {
            const float res = (p == 0 ? n0 : (p == 1 ? n1 : n2)) / den;
            out[((size_t)(b * 18 + n * 3 + p) * HH + (tx + (qi >> 4))) * (size_t)(HH * HH)
                + (size_t)(ty + ((qi >> 2) & 3)) * HH + (tz + (qi & 3))] = res;
        }
    }
}

} // namespace

extern "C" void kernel_launch(void* const* d_in, const int* in_sizes, int n_in,
                              void* d_out, int out_size, void* d_ws, size_t ws_size,
                              hipStream_t stream)
{
    (void)in_sizes; (void)n_in; (void)d_ws; (void)ws_size; (void)out_size;
    const float* q   = (const float*)d_in[0];
    const float* k   = (const float*)d_in[1];
    const float* rpb = (const float*)d_in[2];
    const float* vv  = (const float*)d_in[3];
    float* out = (float*)d_out;

    natten_mfma6<<<dim3(NBLK), dim3(256), 0, stream>>>(q, k, rpb, vv, out);
}